// Round 1
// baseline (728.149 us; speedup 1.0000x reference)
//
#include <hip/hip_runtime.h>
#include <hip/hip_bf16.h>

#define EMBED  2048
#define SEQ    2048
#define BATCH  2
#define NHEADS 16
#define HDIM   128
#define QKVC   (3*EMBED)    // 6144
#define ROWS   (BATCH*SEQ)  // 4096

typedef __attribute__((ext_vector_type(8))) short bf16x8;
typedef __attribute__((ext_vector_type(4))) float f32x4;

typedef const __attribute__((address_space(1))) void* gptr1_t;
typedef __attribute__((address_space(3))) void* lptr3_t;

__device__ __forceinline__ void gld16(const unsigned short* g, unsigned short* l) {
  __builtin_amdgcn_global_load_lds((gptr1_t)g, (lptr3_t)l, 16, 0, 0);
}

__device__ __forceinline__ unsigned short f2bf(float f) {
  unsigned int x = __float_as_uint(f);
  unsigned int r = (x + 0x7fffu + ((x >> 16) & 1u)) >> 16;
  return (unsigned short)r;
}

// ---------------- cast x -> bf16 ----------------
__global__ void cast_kernel(const float* __restrict__ in, unsigned short* __restrict__ out, int n4) {
  int i = blockIdx.x * 256 + threadIdx.x;
  if (i >= n4) return;
  float4 v = reinterpret_cast<const float4*>(in)[i];
  ushort4 o;
  o.x = f2bf(v.x); o.y = f2bf(v.y); o.z = f2bf(v.z); o.w = f2bf(v.w);
  reinterpret_cast<ushort4*>(out)[i] = o;
}

// ---------------- transpose + cast W [R][C] f32 -> [C][R] bf16 ----------------
__global__ void transpose_cast_kernel(const float* __restrict__ in, unsigned short* __restrict__ out,
                                      int R, int C) {
  __shared__ float tile[32][33];
  int tx = threadIdx.x & 31, ty = threadIdx.x >> 5;   // 32 x 8
  int c0 = blockIdx.x * 32, r0 = blockIdx.y * 32;
  #pragma unroll
  for (int i = 0; i < 32; i += 8)
    tile[ty + i][tx] = in[(size_t)(r0 + ty + i) * C + c0 + tx];
  __syncthreads();
  #pragma unroll
  for (int i = 0; i < 32; i += 8)
    out[(size_t)(c0 + ty + i) * R + r0 + tx] = f2bf(tile[tx][ty + i]);
}

// ---------------- MFMA GEMM: C[M][N] = A[M][K] * BT[N][K]^T + bias ----------------
// 128x128 tile, BK=32, 4 waves in 2x2, each wave 64x64 (4x4 of 16x16x32 mfma)
template<int OUTMODE>   // 0: bf16 out, 1: f32 out
__global__ __launch_bounds__(256)
void gemm_kernel(const unsigned short* __restrict__ A,
                 const unsigned short* __restrict__ BT,
                 const float* __restrict__ bias,
                 unsigned short* __restrict__ outb,
                 float* __restrict__ outf,
                 int M, int N, int K) {
  __shared__ unsigned short As[128 * 32];
  __shared__ unsigned short Bs[128 * 32];
  const int t = threadIdx.x;
  const int lane = t & 63, wave = t >> 6;
  const int quad = lane >> 4, l16 = lane & 15;
  const int wm = wave >> 1, wn = wave & 1;
  const int m0 = blockIdx.y * 128, n0 = blockIdx.x * 128;

  f32x4 acc[4][4] = {};

  // swizzled LDS read offsets: row stores chunk dc at position sc = dc ^ p(row), p(row)=((row>>2)^row)&3
  int a_off[4], b_off[4];
  #pragma unroll
  for (int i = 0; i < 4; ++i) {
    int m = wm * 64 + i * 16 + l16;
    int sa = quad ^ (((m >> 2) ^ m) & 3);
    a_off[i] = (m * 4 + sa) * 8;
    int n = wn * 64 + i * 16 + l16;
    int sb = quad ^ (((n >> 2) ^ n) & 3);
    b_off[i] = (n * 4 + sb) * 8;
  }
  // staging mapping (2 chunks of 16B per thread per matrix)
  const int cc0 = t, cc1 = 256 + t;
  const int r0 = cc0 >> 2, s0 = cc0 & 3, d0 = s0 ^ (((r0 >> 2) ^ r0) & 3);
  const int r1 = cc1 >> 2, s1 = cc1 & 3, d1 = s1 ^ (((r1 >> 2) ^ r1) & 3);
  const unsigned short* Ag0 = A  + (size_t)(m0 + r0) * K + d0 * 8;
  const unsigned short* Ag1 = A  + (size_t)(m0 + r1) * K + d1 * 8;
  const unsigned short* Bg0 = BT + (size_t)(n0 + r0) * K + d0 * 8;
  const unsigned short* Bg1 = BT + (size_t)(n0 + r1) * K + d1 * 8;

  for (int k0 = 0; k0 < K; k0 += 32) {
    gld16(Ag0 + k0, &As[cc0 * 8]);
    gld16(Ag1 + k0, &As[cc1 * 8]);
    gld16(Bg0 + k0, &Bs[cc0 * 8]);
    gld16(Bg1 + k0, &Bs[cc1 * 8]);
    __syncthreads();
    bf16x8 af[4], bfr[4];
    #pragma unroll
    for (int i = 0; i < 4; ++i) af[i]  = *(const bf16x8*)&As[a_off[i]];
    #pragma unroll
    for (int i = 0; i < 4; ++i) bfr[i] = *(const bf16x8*)&Bs[b_off[i]];
    #pragma unroll
    for (int i = 0; i < 4; ++i)
      #pragma unroll
      for (int j = 0; j < 4; ++j)
        acc[i][j] = __builtin_amdgcn_mfma_f32_16x16x32_bf16(af[i], bfr[j], acc[i][j], 0, 0, 0);
    __syncthreads();
  }

  #pragma unroll
  for (int i = 0; i < 4; ++i) {
    int row = m0 + wm * 64 + i * 16 + quad * 4;
    #pragma unroll
    for (int j = 0; j < 4; ++j) {
      int col = n0 + wn * 64 + j * 16 + l16;
      float bv = bias[col];
      #pragma unroll
      for (int r = 0; r < 4; ++r) {
        float v = acc[i][j][r] + bv;
        if (OUTMODE == 0) outb[(size_t)(row + r) * N + col] = f2bf(v);
        else              outf[(size_t)(row + r) * N + col] = v;
      }
    }
  }
}

// ---------------- flash attention ----------------
// block: 4 waves x 16 q-rows = 64 q rows for one (b,h); KV tiles of 64
__global__ __launch_bounds__(256)
void attn_kernel(const unsigned short* __restrict__ qkv, unsigned short* __restrict__ outb) {
  __shared__ unsigned short Ks[64 * 128];      // [kv][d], 16B-chunk swizzled
  __shared__ unsigned short Vt[128 * 72];      // [d][kv], stride 72
  __shared__ unsigned short Ps[4][16 * 72];    // per-wave P tile [qrow][kv], stride 72
  const int t = threadIdx.x;
  const int lane = t & 63, wave = t >> 6;
  const int quad = lane >> 4, l16 = lane & 15;
  const int bx = blockIdx.x;
  const int bh = blockIdx.y;
  const int b = bh >> 4, h = bh & 15;
  const size_t rowbase = (size_t)b * SEQ;
  const int qb0 = bx * 64;
  const int qw0 = qb0 + wave * 16;
  const int hq = h * HDIM;

  // Q fragments (A-layout): m = l16, k = s*32 + quad*8 + j
  bf16x8 qf[4];
  {
    const unsigned short* qrow = qkv + (rowbase + qw0 + l16) * QKVC + hq + quad * 8;
    #pragma unroll
    for (int s = 0; s < 4; ++s) qf[s] = *(const bf16x8*)(qrow + s * 32);
  }

  f32x4 o[8] = {};
  float mrow[4], lrow[4];
  #pragma unroll
  for (int r = 0; r < 4; ++r) { mrow[r] = -1e30f; lrow[r] = 0.f; }

  const float SC = 0.08838834764831845f * 1.4426950408889634f; // 1/sqrt(128) * log2(e)

  for (int j = 0; j <= bx; ++j) {
    const int kv0 = j * 64;
    __syncthreads();  // previous iteration's LDS reads done
    // stage K tile, swizzled chunks: position sc in row kv holds global chunk sc^(kv&15)
    #pragma unroll
    for (int i = 0; i < 4; ++i) {
      int cc = i * 256 + t;
      int kv = cc >> 4, sc = cc & 15;
      int dc = sc ^ (kv & 15);
      gld16(qkv + (rowbase + kv0 + kv) * QKVC + EMBED + hq + dc * 8, &Ks[cc * 8]);
    }
    // stage V transposed: Vt[d][kv]
    #pragma unroll
    for (int i = 0; i < 4; ++i) {
      int cc = i * 256 + t;
      int kv = cc >> 4, d8 = (cc & 15) * 8;
      bf16x8 v = *(const bf16x8*)(qkv + (rowbase + kv0 + kv) * QKVC + 2 * EMBED + hq + d8);
      #pragma unroll
      for (int e = 0; e < 8; ++e)
        Vt[(d8 + e) * 72 + kv] = (unsigned short)v[e];
    }
    __syncthreads();

    // S = Q K^T  (per wave: 16 x 64 scores)
    f32x4 sacc[4] = {};
    #pragma unroll
    for (int nb = 0; nb < 4; ++nb) {
      int kv = nb * 16 + l16;
      #pragma unroll
      for (int s = 0; s < 4; ++s) {
        int dc = s * 4 + quad;
        int sc2 = dc ^ (kv & 15);
        bf16x8 kb = *(const bf16x8*)&Ks[(kv * 16 + sc2) * 8];
        sacc[nb] = __builtin_amdgcn_mfma_f32_16x16x32_bf16(qf[s], kb, sacc[nb], 0, 0, 0);
      }
    }

    // scale + causal mask + online softmax (exp2 domain)
    float p[4][4], rmax[4];
    const bool maskt = (j == bx);
    #pragma unroll
    for (int r = 0; r < 4; ++r) rmax[r] = -1e30f;
    #pragma unroll
    for (int nb = 0; nb < 4; ++nb) {
      int kvg = kv0 + nb * 16 + l16;
      #pragma unroll
      for (int r = 0; r < 4; ++r) {
        float s2 = sacc[nb][r] * SC;
        int qg = qw0 + quad * 4 + r;
        if (maskt && kvg > qg) s2 = -1e30f;
        p[nb][r] = s2;
        rmax[r] = fmaxf(rmax[r], s2);
      }
    }
    #pragma unroll
    for (int r = 0; r < 4; ++r)
      #pragma unroll
      for (int off = 1; off < 16; off <<= 1)
        rmax[r] = fmaxf(rmax[r], __shfl_xor(rmax[r], off, 16));

    float alpha[4];
    #pragma unroll
    for (int r = 0; r < 4; ++r) {
      float mnew = fmaxf(mrow[r], rmax[r]);
      alpha[r] = exp2f(mrow[r] - mnew);
      mrow[r] = mnew;
      float s = 0.f;
      #pragma unroll
      for (int nb = 0; nb < 4; ++nb) {
        float pv = exp2f(p[nb][r] - mnew);
        p[nb][r] = pv;
        s += pv;
      }
      #pragma unroll
      for (int off = 1; off < 16; off <<= 1)
        s += __shfl_xor(s, off, 16);
      lrow[r] = lrow[r] * alpha[r] + s;
    }
    #pragma unroll
    for (int d = 0; d < 8; ++d)
      #pragma unroll
      for (int r = 0; r < 4; ++r)
        o[d][r] *= alpha[r];

    // P: C-layout -> LDS -> A-layout
    unsigned short* pw = &Ps[wave][0];
    #pragma unroll
    for (int nb = 0; nb < 4; ++nb)
      #pragma unroll
      for (int r = 0; r < 4; ++r)
        pw[(quad * 4 + r) * 72 + nb * 16 + l16] = f2bf(p[nb][r]);
    asm volatile("s_waitcnt lgkmcnt(0)" ::: "memory");
    bf16x8 pa[2];
    #pragma unroll
    for (int ks = 0; ks < 2; ++ks)
      pa[ks] = *(const bf16x8*)&pw[l16 * 72 + ks * 32 + quad * 8];

    // O += P V
    #pragma unroll
    for (int d = 0; d < 8; ++d)
      #pragma unroll
      for (int ks = 0; ks < 2; ++ks) {
        bf16x8 vb = *(const bf16x8*)&Vt[(d * 16 + l16) * 72 + ks * 32 + quad * 8];
        o[d] = __builtin_amdgcn_mfma_f32_16x16x32_bf16(pa[ks], vb, o[d], 0, 0, 0);
      }
  }

  // normalize + store bf16 [b*S+q][h*128+d]
  #pragma unroll
  for (int d = 0; d < 8; ++d)
    #pragma unroll
    for (int r = 0; r < 4; ++r) {
      size_t row = rowbase + qw0 + quad * 4 + r;
      outb[row * EMBED + hq + d * 16 + l16] = f2bf(o[d][r] / lrow[r]);
    }
}

extern "C" void kernel_launch(void* const* d_in, const int* in_sizes, int n_in,
                              void* d_out, int out_size, void* d_ws, size_t ws_size,
                              hipStream_t stream) {
  const float* x    = (const float*)d_in[0];
  const float* Wqkv = (const float*)d_in[1];
  const float* bqkv = (const float*)d_in[2];
  const float* Wout = (const float*)d_in[3];
  const float* bout = (const float*)d_in[4];
  float* out = (float*)d_out;

  unsigned short* xb    = (unsigned short*)d_ws;
  unsigned short* wqkvT = xb    + (size_t)ROWS * EMBED;   // [6144][2048]
  unsigned short* woutT = wqkvT + (size_t)EMBED * QKVC;   // [2048][2048]
  unsigned short* qkvb  = woutT + (size_t)EMBED * EMBED;  // [4096][6144]
  unsigned short* attnb = qkvb  + (size_t)ROWS * QKVC;    // [4096][2048]
  // total: 117,440,512 bytes of d_ws

  cast_kernel<<<dim3((ROWS * EMBED / 4 + 255) / 256), 256, 0, stream>>>(x, xb, ROWS * EMBED / 4);
  transpose_cast_kernel<<<dim3(QKVC / 32, EMBED / 32), 256, 0, stream>>>(Wqkv, wqkvT, EMBED, QKVC);
  transpose_cast_kernel<<<dim3(EMBED / 32, EMBED / 32), 256, 0, stream>>>(Wout, woutT, EMBED, EMBED);

  gemm_kernel<0><<<dim3(QKVC / 128, ROWS / 128), 256, 0, stream>>>(
      xb, wqkvT, bqkv, qkvb, nullptr, ROWS, QKVC, EMBED);

  attn_kernel<<<dim3(SEQ / 64, BATCH * NHEADS), 256, 0, stream>>>(qkvb, attnb);

  gemm_kernel<1><<<dim3(EMBED / 128, ROWS / 128), 256, 0, stream>>>(
      attnb, woutT, bout, nullptr, out, ROWS, EMBED, EMBED);
}

// Round 3
// 477.148 us; speedup vs baseline: 1.5260x; 1.5260x over previous
//
#include <hip/hip_runtime.h>
#include <hip/hip_bf16.h>

#define EMBED  2048
#define SEQ    2048
#define BATCH  2
#define NHEADS 16
#define HDIM   128
#define QKVC   (3*EMBED)    // 6144
#define ROWS   (BATCH*SEQ)  // 4096

typedef __attribute__((ext_vector_type(8))) short bf16x8;
typedef __attribute__((ext_vector_type(4))) float f32x4;

typedef const __attribute__((address_space(1))) void* gptr1_t;
typedef __attribute__((address_space(3))) void* lptr3_t;

__device__ __forceinline__ void gld16(const unsigned short* g, unsigned short* l) {
  __builtin_amdgcn_global_load_lds((gptr1_t)g, (lptr3_t)l, 16, 0, 0);
}

__device__ __forceinline__ unsigned short f2bf(float f) {
  unsigned int x = __float_as_uint(f);
  unsigned int r = (x + 0x7fffu + ((x >> 16) & 1u)) >> 16;
  return (unsigned short)r;
}

// ---------------- cast x -> bf16 ----------------
__global__ void cast_kernel(const float* __restrict__ in, unsigned short* __restrict__ out, int n4) {
  int i = blockIdx.x * 256 + threadIdx.x;
  if (i >= n4) return;
  float4 v = reinterpret_cast<const float4*>(in)[i];
  ushort4 o;
  o.x = f2bf(v.x); o.y = f2bf(v.y); o.z = f2bf(v.z); o.w = f2bf(v.w);
  reinterpret_cast<ushort4*>(out)[i] = o;
}

// ---------------- transpose + cast W [R][C] f32 -> [C][R] bf16 ----------------
__global__ void transpose_cast_kernel(const float* __restrict__ in, unsigned short* __restrict__ out,
                                      int R, int C) {
  __shared__ float tile[32][33];
  int tx = threadIdx.x & 31, ty = threadIdx.x >> 5;   // 32 x 8
  int c0 = blockIdx.x * 32, r0 = blockIdx.y * 32;
  #pragma unroll
  for (int i = 0; i < 32; i += 8)
    tile[ty + i][tx] = in[(size_t)(r0 + ty + i) * C + c0 + tx];
  __syncthreads();
  #pragma unroll
  for (int i = 0; i < 32; i += 8)
    out[(size_t)(c0 + ty + i) * R + r0 + tx] = f2bf(tile[tx][ty + i]);
}

// ---------------- MFMA GEMM: C[M][N] = A[M][K] * BT[N][K]^T + bias ----------------
// 128x128 tile, BK=32, 4 waves in 2x2, each wave 64x64 (4x4 of 16x16x32 mfma)
// MODE 0: QKV gemm: cols<4096 -> bf16 qk buffer (row stride 4096); cols>=4096 -> V transposed to vt
// MODE 1: f32 out, row stride N
template<int MODE>
__global__ __launch_bounds__(256)
void gemm_kernel(const unsigned short* __restrict__ A,
                 const unsigned short* __restrict__ BT,
                 const float* __restrict__ bias,
                 unsigned short* __restrict__ outb,
                 unsigned short* __restrict__ vt,
                 float* __restrict__ outf,
                 int M, int N, int K) {
  __shared__ unsigned short As[128 * 32];
  __shared__ unsigned short Bs[128 * 32];
  const int t = threadIdx.x;
  const int lane = t & 63, wave = t >> 6;
  const int quad = lane >> 4, l16 = lane & 15;
  const int wm = wave >> 1, wn = wave & 1;
  const int m0 = blockIdx.y * 128, n0 = blockIdx.x * 128;

  f32x4 acc[4][4] = {};

  int a_off[4], b_off[4];
  #pragma unroll
  for (int i = 0; i < 4; ++i) {
    int m = wm * 64 + i * 16 + l16;
    int sa = quad ^ (((m >> 2) ^ m) & 3);
    a_off[i] = (m * 4 + sa) * 8;
    int n = wn * 64 + i * 16 + l16;
    int sb = quad ^ (((n >> 2) ^ n) & 3);
    b_off[i] = (n * 4 + sb) * 8;
  }
  const int cc0 = t, cc1 = 256 + t;
  const int r0 = cc0 >> 2, s0 = cc0 & 3, d0 = s0 ^ (((r0 >> 2) ^ r0) & 3);
  const int r1 = cc1 >> 2, s1 = cc1 & 3, d1 = s1 ^ (((r1 >> 2) ^ r1) & 3);
  const unsigned short* Ag0 = A  + (size_t)(m0 + r0) * K + d0 * 8;
  const unsigned short* Ag1 = A  + (size_t)(m0 + r1) * K + d1 * 8;
  const unsigned short* Bg0 = BT + (size_t)(n0 + r0) * K + d0 * 8;
  const unsigned short* Bg1 = BT + (size_t)(n0 + r1) * K + d1 * 8;

  for (int k0 = 0; k0 < K; k0 += 32) {
    gld16(Ag0 + k0, &As[cc0 * 8]);
    gld16(Ag1 + k0, &As[cc1 * 8]);
    gld16(Bg0 + k0, &Bs[cc0 * 8]);
    gld16(Bg1 + k0, &Bs[cc1 * 8]);
    __syncthreads();
    bf16x8 af[4], bfr[4];
    #pragma unroll
    for (int i = 0; i < 4; ++i) af[i]  = *(const bf16x8*)&As[a_off[i]];
    #pragma unroll
    for (int i = 0; i < 4; ++i) bfr[i] = *(const bf16x8*)&Bs[b_off[i]];
    #pragma unroll
    for (int i = 0; i < 4; ++i)
      #pragma unroll
      for (int j = 0; j < 4; ++j)
        acc[i][j] = __builtin_amdgcn_mfma_f32_16x16x32_bf16(af[i], bfr[j], acc[i][j], 0, 0, 0);
    __syncthreads();
  }

  #pragma unroll
  for (int i = 0; i < 4; ++i) {
    int row = m0 + wm * 64 + i * 16 + quad * 4;
    #pragma unroll
    for (int j = 0; j < 4; ++j) {
      int col = n0 + wn * 64 + j * 16 + l16;
      float bv = bias[col];
      if (MODE == 1) {
        #pragma unroll
        for (int r = 0; r < 4; ++r)
          outf[(size_t)(row + r) * N + col] = acc[i][j][r] + bv;
      } else if (n0 < 2 * EMBED) {
        // Q,K region: row stride 4096
        #pragma unroll
        for (int r = 0; r < 4; ++r)
          outb[(size_t)(row + r) * 4096 + col] = f2bf(acc[i][j][r] + bv);
      } else {
        // V region: write transposed into vt[bh*128+d][s]
        int hd = col - 2 * EMBED;
        int b = row >> 11, s = row & 2047;
        ushort4 w;
        w.x = f2bf(acc[i][j][0] + bv);
        w.y = f2bf(acc[i][j][1] + bv);
        w.z = f2bf(acc[i][j][2] + bv);
        w.w = f2bf(acc[i][j][3] + bv);
        // hd = h*128 + d ; vt row index = b*2048 + hd
        *(ushort4*)&vt[(((size_t)(b << 11) + hd) << 11) + s] = w;
      }
    }
  }
}

// ---------------- flash attention (S^T form) ----------------
// block: 4 waves x 16 q-rows = 64 q rows; KV tiles of 64
// grid.x = 16 (q-tile pairs p and 31-p), grid.y = 32 (b*16+h)
__global__ __launch_bounds__(256)
void attn_kernel(const unsigned short* __restrict__ qk,   // [4096][4096] Q|K bf16
                 const unsigned short* __restrict__ vt,   // [32*128][2048] V^T bf16
                 unsigned short* __restrict__ outb) {     // [4096][2048] bf16
  __shared__ unsigned short Ks[64 * 128];   // [kv][d] chunk-swizzled, 16KB
  __shared__ unsigned short Vs[64 * 128];   // [d][kv] chunk-swizzled, 16KB
  __shared__ unsigned short Ps[4][16 * 72]; // per-wave P [q][kv], stride 72
  const int t = threadIdx.x;
  const int lane = t & 63, wave = t >> 6;
  const int quad = lane >> 4, l16 = lane & 15;
  const int bx = blockIdx.x;
  const int bh = blockIdx.y;
  const int b = bh >> 4, h = bh & 15;
  const size_t rowbase = (size_t)b * SEQ;
  const int hq = h * HDIM;
  const unsigned short* vbase = vt + ((size_t)bh * HDIM) * SEQ;

  const float SC = 0.08838834764831845f * 1.4426950408889634f; // 1/sqrt(128)*log2(e)

  #pragma unroll
  for (int half = 0; half < 2; ++half) {
    const int qt = half ? (31 - bx) : bx;
    const int qw0 = qt * 64 + wave * 16;

    // Q fragments (B-operand): lane n = l16 = q, k = ks*32 + quad*8 + j
    bf16x8 qf[4];
    {
      const unsigned short* qrow = qk + (size_t)(rowbase + qw0 + l16) * 4096 + hq + quad * 8;
      #pragma unroll
      for (int s = 0; s < 4; ++s) qf[s] = *(const bf16x8*)(qrow + s * 32);
    }

    f32x4 o[8] = {};
    float mrow = -1e30f, lrow = 0.f;

    for (int j = 0; j <= qt; ++j) {
      const int kv0 = j * 64;
      __syncthreads();  // previous iteration's K/V LDS reads done
      // stage K tile: slot cc = kv*16 + sc, holds global d-chunk sc^(kv&15)
      // K lives at column offset EMBED (row stride 4096: [Q | K])
      #pragma unroll
      for (int i = 0; i < 4; ++i) {
        int cc = i * 256 + t;
        int kv = cc >> 4, sc = cc & 15;
        int dc = sc ^ (kv & 15);
        gld16(qk + (size_t)(rowbase + kv0 + kv) * 4096 + EMBED + hq + dc * 8, &Ks[cc * 8]);
      }
      // stage V^T tile: slot cc = d*8 + c, holds global kv-chunk c^(d&7)
      #pragma unroll
      for (int i = 0; i < 4; ++i) {
        int cc = i * 256 + t;
        int d = cc >> 3, c = cc & 7;
        int dc = c ^ (d & 7);
        gld16(vbase + (size_t)d * SEQ + kv0 + dc * 8, &Vs[cc * 8]);
      }
      __syncthreads();

      // S^T = K Q^T : D[m=kv][n=q]; per nb: kv block nb*16
      f32x4 sacc[4] = {};
      #pragma unroll
      for (int nb = 0; nb < 4; ++nb) {
        int kvr = nb * 16 + l16;
        #pragma unroll
        for (int ks = 0; ks < 4; ++ks) {
          int dc2 = (ks * 4 + quad) ^ (kvr & 15);
          bf16x8 kb = *(const bf16x8*)&Ks[(kvr * 16 + dc2) * 8];
          sacc[nb] = __builtin_amdgcn_mfma_f32_16x16x32_bf16(kb, qf[ks], sacc[nb], 0, 0, 0);
        }
      }

      // softmax: per-lane q = l16; kv = kv0 + nb*16 + quad*4 + r
      const bool diag = (j == qt);
      const int qg = qw0 + l16;
      float p[4][4];
      float smax = -1e30f;
      #pragma unroll
      for (int nb = 0; nb < 4; ++nb)
        #pragma unroll
        for (int r = 0; r < 4; ++r) {
          float v = sacc[nb][r] * SC;
          if (diag && (kv0 + nb * 16 + quad * 4 + r) > qg) v = -1e30f;
          p[nb][r] = v;
          smax = fmaxf(smax, v);
        }
      smax = fmaxf(smax, __shfl_xor(smax, 16));
      smax = fmaxf(smax, __shfl_xor(smax, 32));

      float mnew = fmaxf(mrow, smax);
      float alpha = exp2f(mrow - mnew);
      mrow = mnew;
      float rs = 0.f;
      #pragma unroll
      for (int nb = 0; nb < 4; ++nb)
        #pragma unroll
        for (int r = 0; r < 4; ++r) {
          float pv = exp2f(p[nb][r] - mnew);
          p[nb][r] = pv;
          rs += pv;
        }
      rs += __shfl_xor(rs, 16);
      rs += __shfl_xor(rs, 32);
      lrow = lrow * alpha + rs;

      // write P (A-layout source): Ps[q][kv], 4x ds_write_b64
      unsigned short* pw = &Ps[wave][0];
      #pragma unroll
      for (int nb = 0; nb < 4; ++nb) {
        ushort4 w;
        w.x = f2bf(p[nb][0]); w.y = f2bf(p[nb][1]);
        w.z = f2bf(p[nb][2]); w.w = f2bf(p[nb][3]);
        *(ushort4*)&pw[l16 * 72 + nb * 16 + quad * 4] = w;
      }

      // rescale O (rows q = quad*4 + r)
      #pragma unroll
      for (int r = 0; r < 4; ++r) {
        float av = __shfl(alpha, quad * 4 + r, 16);
        #pragma unroll
        for (int db = 0; db < 8; ++db) o[db][r] *= av;
      }

      asm volatile("s_waitcnt lgkmcnt(0)" ::: "memory");
      bf16x8 pa[2];
      #pragma unroll
      for (int ks2 = 0; ks2 < 2; ++ks2)
        pa[ks2] = *(const bf16x8*)&pw[l16 * 72 + ks2 * 32 + quad * 8];

      // O += P V : D[m=q][n=d]; B-frag = V^T[d][kv]
      #pragma unroll
      for (int db = 0; db < 8; ++db) {
        int d = db * 16 + l16;
        #pragma unroll
        for (int ks2 = 0; ks2 < 2; ++ks2) {
          int dc = (ks2 * 4 + quad) ^ (d & 7);
          bf16x8 vb = *(const bf16x8*)&Vs[(d * 8 + dc) * 8];
          o[db] = __builtin_amdgcn_mfma_f32_16x16x32_bf16(pa[ks2], vb, o[db], 0, 0, 0);
        }
      }
    }

    // epilogue: rows q = quad*4+r, cols d = db*16+l16
    #pragma unroll
    for (int r = 0; r < 4; ++r) {
      float lr = __shfl(lrow, quad * 4 + r, 16);
      float inv = 1.0f / lr;
      size_t row = rowbase + qw0 + quad * 4 + r;
      #pragma unroll
      for (int db = 0; db < 8; ++db)
        outb[row * EMBED + hq + db * 16 + l16] = f2bf(o[db][r] * inv);
    }
    __syncthreads();  // protect LDS before second half restages
  }
}

extern "C" void kernel_launch(void* const* d_in, const int* in_sizes, int n_in,
                              void* d_out, int out_size, void* d_ws, size_t ws_size,
                              hipStream_t stream) {
  const float* x    = (const float*)d_in[0];
  const float* Wqkv = (const float*)d_in[1];
  const float* bqkv = (const float*)d_in[2];
  const float* Wout = (const float*)d_in[3];
  const float* bout = (const float*)d_in[4];
  float* out = (float*)d_out;

  unsigned short* xb    = (unsigned short*)d_ws;
  unsigned short* wqkvT = xb    + (size_t)ROWS * EMBED;    // [6144][2048]
  unsigned short* woutT = wqkvT + (size_t)EMBED * QKVC;    // [2048][2048]
  unsigned short* qkb   = woutT + (size_t)EMBED * EMBED;   // [4096][4096] Q|K
  unsigned short* vtb   = qkb   + (size_t)ROWS * 4096;     // [32*128][2048] V^T
  unsigned short* attnb = vtb   + (size_t)32 * HDIM * SEQ; // [4096][2048]
  // total ~117.4 MB

  cast_kernel<<<dim3((ROWS * EMBED / 4 + 255) / 256), 256, 0, stream>>>(x, xb, ROWS * EMBED / 4);
  transpose_cast_kernel<<<dim3(QKVC / 32, EMBED / 32), 256, 0, stream>>>(Wqkv, wqkvT, EMBED, QKVC);
  transpose_cast_kernel<<<dim3(EMBED / 32, EMBED / 32), 256, 0, stream>>>(Wout, woutT, EMBED, EMBED);

  gemm_kernel<0><<<dim3(QKVC / 128, ROWS / 128), 256, 0, stream>>>(
      xb, wqkvT, bqkv, qkb, vtb, nullptr, ROWS, QKVC, EMBED);

  attn_kernel<<<dim3(16, BATCH * NHEADS), 256, 0, stream>>>(qkb, vtb, attnb);

  gemm_kernel<1><<<dim3(EMBED / 128, ROWS / 128), 256, 0, stream>>>(
      attnb, woutT, bout, nullptr, nullptr, out, ROWS, EMBED, EMBED);
}

// Round 4
// 420.893 us; speedup vs baseline: 1.7300x; 1.1337x over previous
//
#include <hip/hip_runtime.h>
#include <hip/hip_bf16.h>

#define EMBED  2048
#define SEQ    2048
#define BATCH  2
#define NHEADS 16
#define HDIM   128
#define QKVC   (3*EMBED)    // 6144
#define ROWS   (BATCH*SEQ)  // 4096

typedef __attribute__((ext_vector_type(8))) short bf16x8;
typedef __attribute__((ext_vector_type(4))) float f32x4;

typedef const __attribute__((address_space(1))) void* gptr1_t;
typedef __attribute__((address_space(3))) void* lptr3_t;

__device__ __forceinline__ void gld16(const unsigned short* g, unsigned short* l) {
  __builtin_amdgcn_global_load_lds((gptr1_t)g, (lptr3_t)l, 16, 0, 0);
}

__device__ __forceinline__ unsigned short f2bf(float f) {
  unsigned int x = __float_as_uint(f);
  unsigned int r = (x + 0x7fffu + ((x >> 16) & 1u)) >> 16;
  return (unsigned short)r;
}

// ---------------- cast x -> bf16 ----------------
__global__ void cast_kernel(const float* __restrict__ in, unsigned short* __restrict__ out, int n4) {
  int i = blockIdx.x * 256 + threadIdx.x;
  if (i >= n4) return;
  float4 v = reinterpret_cast<const float4*>(in)[i];
  ushort4 o;
  o.x = f2bf(v.x); o.y = f2bf(v.y); o.z = f2bf(v.z); o.w = f2bf(v.w);
  reinterpret_cast<ushort4*>(out)[i] = o;
}

// ---------------- transpose + cast W [R][C] f32 -> [C][R] bf16 ----------------
__global__ void transpose_cast_kernel(const float* __restrict__ in, unsigned short* __restrict__ out,
                                      int R, int C) {
  __shared__ float tile[32][33];
  int tx = threadIdx.x & 31, ty = threadIdx.x >> 5;   // 32 x 8
  int c0 = blockIdx.x * 32, r0 = blockIdx.y * 32;
  #pragma unroll
  for (int i = 0; i < 32; i += 8)
    tile[ty + i][tx] = in[(size_t)(r0 + ty + i) * C + c0 + tx];
  __syncthreads();
  #pragma unroll
  for (int i = 0; i < 32; i += 8)
    out[(size_t)(c0 + ty + i) * R + r0 + tx] = f2bf(tile[tx][ty + i]);
}

// ---------------- MFMA GEMM: C[M][N] = A[M][K] * BT[N][K]^T + bias ----------------
template<int MODE>
__global__ __launch_bounds__(256)
void gemm_kernel(const unsigned short* __restrict__ A,
                 const unsigned short* __restrict__ BT,
                 const float* __restrict__ bias,
                 unsigned short* __restrict__ outb,
                 unsigned short* __restrict__ vt,
                 float* __restrict__ outf,
                 int M, int N, int K) {
  __shared__ unsigned short As[128 * 32];
  __shared__ unsigned short Bs[128 * 32];
  const int t = threadIdx.x;
  const int lane = t & 63, wave = t >> 6;
  const int quad = lane >> 4, l16 = lane & 15;
  const int wm = wave >> 1, wn = wave & 1;
  const int m0 = blockIdx.y * 128, n0 = blockIdx.x * 128;

  f32x4 acc[4][4] = {};

  int a_off[4], b_off[4];
  #pragma unroll
  for (int i = 0; i < 4; ++i) {
    int m = wm * 64 + i * 16 + l16;
    int sa = quad ^ (((m >> 2) ^ m) & 3);
    a_off[i] = (m * 4 + sa) * 8;
    int n = wn * 64 + i * 16 + l16;
    int sb = quad ^ (((n >> 2) ^ n) & 3);
    b_off[i] = (n * 4 + sb) * 8;
  }
  const int cc0 = t, cc1 = 256 + t;
  const int r0 = cc0 >> 2, s0 = cc0 & 3, d0 = s0 ^ (((r0 >> 2) ^ r0) & 3);
  const int r1 = cc1 >> 2, s1 = cc1 & 3, d1 = s1 ^ (((r1 >> 2) ^ r1) & 3);
  const unsigned short* Ag0 = A  + (size_t)(m0 + r0) * K + d0 * 8;
  const unsigned short* Ag1 = A  + (size_t)(m0 + r1) * K + d1 * 8;
  const unsigned short* Bg0 = BT + (size_t)(n0 + r0) * K + d0 * 8;
  const unsigned short* Bg1 = BT + (size_t)(n0 + r1) * K + d1 * 8;

  for (int k0 = 0; k0 < K; k0 += 32) {
    gld16(Ag0 + k0, &As[cc0 * 8]);
    gld16(Ag1 + k0, &As[cc1 * 8]);
    gld16(Bg0 + k0, &Bs[cc0 * 8]);
    gld16(Bg1 + k0, &Bs[cc1 * 8]);
    __syncthreads();
    bf16x8 af[4], bfr[4];
    #pragma unroll
    for (int i = 0; i < 4; ++i) af[i]  = *(const bf16x8*)&As[a_off[i]];
    #pragma unroll
    for (int i = 0; i < 4; ++i) bfr[i] = *(const bf16x8*)&Bs[b_off[i]];
    #pragma unroll
    for (int i = 0; i < 4; ++i)
      #pragma unroll
      for (int j = 0; j < 4; ++j)
        acc[i][j] = __builtin_amdgcn_mfma_f32_16x16x32_bf16(af[i], bfr[j], acc[i][j], 0, 0, 0);
    __syncthreads();
  }

  #pragma unroll
  for (int i = 0; i < 4; ++i) {
    int row = m0 + wm * 64 + i * 16 + quad * 4;
    #pragma unroll
    for (int j = 0; j < 4; ++j) {
      int col = n0 + wn * 64 + j * 16 + l16;
      float bv = bias[col];
      if (MODE == 1) {
        #pragma unroll
        for (int r = 0; r < 4; ++r)
          outf[(size_t)(row + r) * N + col] = acc[i][j][r] + bv;
      } else if (n0 < 2 * EMBED) {
        #pragma unroll
        for (int r = 0; r < 4; ++r)
          outb[(size_t)(row + r) * 4096 + col] = f2bf(acc[i][j][r] + bv);
      } else {
        int hd = col - 2 * EMBED;
        int b = row >> 11, s = row & 2047;
        ushort4 w;
        w.x = f2bf(acc[i][j][0] + bv);
        w.y = f2bf(acc[i][j][1] + bv);
        w.z = f2bf(acc[i][j][2] + bv);
        w.w = f2bf(acc[i][j][3] + bv);
        *(ushort4*)&vt[(((size_t)(b << 11) + hd) << 11) + s] = w;
      }
    }
  }
}

// ---------------- flash attention (S^T form, double-buffered K/V) ----------------
// grid: (x=32 bh, y=16 q-tile pairs) -> same-bh blocks on same XCD (linear id mod 8)
__global__ __launch_bounds__(256)
void attn_kernel(const unsigned short* __restrict__ qk,   // [4096][4096] Q|K bf16
                 const unsigned short* __restrict__ vt,   // [32*128][2048] V^T bf16
                 unsigned short* __restrict__ outb) {     // [4096][2048] bf16
  __shared__ unsigned short Ks[2][64 * 128];
  __shared__ unsigned short Vs[2][64 * 128];
  __shared__ unsigned short Ps[4][16 * 72];
  const int t = threadIdx.x;
  const int lane = t & 63, wave = t >> 6;
  const int quad = lane >> 4, l16 = lane & 15;
  const int bh = blockIdx.x;
  const int pair = blockIdx.y;
  const int b = bh >> 4, h = bh & 15;
  const size_t rowbase = (size_t)b * SEQ;
  const int hq = h * HDIM;
  const unsigned short* vbase = vt + ((size_t)bh * HDIM) * SEQ;

  const float SC = 0.08838834764831845f * 1.4426950408889634f; // 1/sqrt(128)*log2(e)

  #pragma unroll
  for (int half = 0; half < 2; ++half) {
    const int qt = half ? (31 - pair) : pair;
    const int qw0 = qt * 64 + wave * 16;

    bf16x8 qf[4];
    {
      const unsigned short* qrow = qk + (size_t)(rowbase + qw0 + l16) * 4096 + hq + quad * 8;
      #pragma unroll
      for (int s = 0; s < 4; ++s) qf[s] = *(const bf16x8*)(qrow + s * 32);
    }

    f32x4 o[8] = {};
    float mrow = -1e30f, lrow = 0.f;

    // prologue: stage tile 0 into buffer 0
    #pragma unroll
    for (int i = 0; i < 4; ++i) {
      int cc = i * 256 + t;
      int kv = cc >> 4, sc = cc & 15;
      int dc = sc ^ (kv & 15);
      gld16(qk + (size_t)(rowbase + kv) * 4096 + EMBED + hq + dc * 8, &Ks[0][cc * 8]);
    }
    #pragma unroll
    for (int i = 0; i < 4; ++i) {
      int cc = i * 256 + t;
      int d = cc >> 3, c = cc & 7;
      int dc = c ^ (d & 7);
      gld16(vbase + (size_t)d * SEQ + dc * 8, &Vs[0][cc * 8]);
    }

    for (int j = 0; j <= qt; ++j) {
      const int cur = j & 1;
      __syncthreads();   // buf[cur] ready; all reads of buf[cur^1] complete

      if (j < qt) {      // prefetch tile j+1, overlapped with compute below
        const int kv1 = (j + 1) * 64;
        #pragma unroll
        for (int i = 0; i < 4; ++i) {
          int cc = i * 256 + t;
          int kv = cc >> 4, sc = cc & 15;
          int dc = sc ^ (kv & 15);
          gld16(qk + (size_t)(rowbase + kv1 + kv) * 4096 + EMBED + hq + dc * 8, &Ks[cur ^ 1][cc * 8]);
        }
        #pragma unroll
        for (int i = 0; i < 4; ++i) {
          int cc = i * 256 + t;
          int d = cc >> 3, c = cc & 7;
          int dc = c ^ (d & 7);
          gld16(vbase + (size_t)d * SEQ + kv1 + dc * 8, &Vs[cur ^ 1][cc * 8]);
        }
      }

      const int kv0 = j * 64;
      f32x4 sacc[4] = {};
      #pragma unroll
      for (int nb = 0; nb < 4; ++nb) {
        int kvr = nb * 16 + l16;
        #pragma unroll
        for (int ks = 0; ks < 4; ++ks) {
          int dc2 = (ks * 4 + quad) ^ (kvr & 15);
          bf16x8 kb = *(const bf16x8*)&Ks[cur][(kvr * 16 + dc2) * 8];
          sacc[nb] = __builtin_amdgcn_mfma_f32_16x16x32_bf16(kb, qf[ks], sacc[nb], 0, 0, 0);
        }
      }

      float p[4][4];
      float smax = -1e30f;
      if (j == qt) {
        const int qg = qw0 + l16;
        #pragma unroll
        for (int nb = 0; nb < 4; ++nb)
          #pragma unroll
          for (int r = 0; r < 4; ++r) {
            float v = sacc[nb][r] * SC;
            if ((kv0 + nb * 16 + quad * 4 + r) > qg) v = -1e30f;
            p[nb][r] = v;
            smax = fmaxf(smax, v);
          }
      } else {
        #pragma unroll
        for (int nb = 0; nb < 4; ++nb)
          #pragma unroll
          for (int r = 0; r < 4; ++r) {
            float v = sacc[nb][r] * SC;
            p[nb][r] = v;
            smax = fmaxf(smax, v);
          }
      }
      smax = fmaxf(smax, __shfl_xor(smax, 16));
      smax = fmaxf(smax, __shfl_xor(smax, 32));

      const float mold = mrow;
      const unsigned long long grew = __ballot(smax > mold);
      const float mnew = fmaxf(mold, smax);
      mrow = mnew;

      float rs = 0.f;
      #pragma unroll
      for (int nb = 0; nb < 4; ++nb)
        #pragma unroll
        for (int r = 0; r < 4; ++r) {
          float pv = exp2f(p[nb][r] - mnew);
          p[nb][r] = pv;
          rs += pv;
        }
      rs += __shfl_xor(rs, 16);
      rs += __shfl_xor(rs, 32);

      unsigned short* pw = &Ps[wave][0];
      #pragma unroll
      for (int nb = 0; nb < 4; ++nb) {
        __hip_bfloat162 lo = __float22bfloat162_rn(make_float2(p[nb][0], p[nb][1]));
        __hip_bfloat162 hi = __float22bfloat162_rn(make_float2(p[nb][2], p[nb][3]));
        ushort4 w;
        w.x = *(unsigned short*)&lo.x; w.y = *(unsigned short*)&lo.y;
        w.z = *(unsigned short*)&hi.x; w.w = *(unsigned short*)&hi.y;
        *(ushort4*)&pw[l16 * 72 + nb * 16 + quad * 4] = w;
      }

      if (grew) {   // wave-uniform: some q-row's max increased -> rescale O and lrow
        float alpha = exp2f(mold - mnew);   // ==1 for rows that didn't grow
        lrow = lrow * alpha + rs;
        #pragma unroll
        for (int r = 0; r < 4; ++r) {
          float av = __shfl(alpha, quad * 4 + r, 16);
          #pragma unroll
          for (int db = 0; db < 8; ++db) o[db][r] *= av;
        }
      } else {
        lrow += rs;
      }

      asm volatile("s_waitcnt lgkmcnt(0)" ::: "memory");
      bf16x8 pa[2];
      #pragma unroll
      for (int ks2 = 0; ks2 < 2; ++ks2)
        pa[ks2] = *(const bf16x8*)&pw[l16 * 72 + ks2 * 32 + quad * 8];

      #pragma unroll
      for (int db = 0; db < 8; ++db) {
        int d = db * 16 + l16;
        #pragma unroll
        for (int ks2 = 0; ks2 < 2; ++ks2) {
          int dc = (ks2 * 4 + quad) ^ (d & 7);
          bf16x8 vb = *(const bf16x8*)&Vs[cur][(d * 8 + dc) * 8];
          o[db] = __builtin_amdgcn_mfma_f32_16x16x32_bf16(pa[ks2], vb, o[db], 0, 0, 0);
        }
      }
    }

    #pragma unroll
    for (int r = 0; r < 4; ++r) {
      float lr = __shfl(lrow, quad * 4 + r, 16);
      float inv = 1.0f / lr;
      size_t row = rowbase + qw0 + quad * 4 + r;
      #pragma unroll
      for (int db = 0; db < 8; ++db)
        outb[row * EMBED + hq + db * 16 + l16] = f2bf(o[db][r] * inv);
    }
    __syncthreads();  // all waves done with buffers before next half restages
  }
}

extern "C" void kernel_launch(void* const* d_in, const int* in_sizes, int n_in,
                              void* d_out, int out_size, void* d_ws, size_t ws_size,
                              hipStream_t stream) {
  const float* x    = (const float*)d_in[0];
  const float* Wqkv = (const float*)d_in[1];
  const float* bqkv = (const float*)d_in[2];
  const float* Wout = (const float*)d_in[3];
  const float* bout = (const float*)d_in[4];
  float* out = (float*)d_out;

  unsigned short* xb    = (unsigned short*)d_ws;
  unsigned short* wqkvT = xb    + (size_t)ROWS * EMBED;    // [6144][2048]
  unsigned short* woutT = wqkvT + (size_t)EMBED * QKVC;    // [2048][2048]
  unsigned short* qkb   = woutT + (size_t)EMBED * EMBED;   // [4096][4096] Q|K
  unsigned short* vtb   = qkb   + (size_t)ROWS * 4096;     // [32*128][2048] V^T
  unsigned short* attnb = vtb   + (size_t)32 * HDIM * SEQ; // [4096][2048]

  cast_kernel<<<dim3((ROWS * EMBED / 4 + 255) / 256), 256, 0, stream>>>(x, xb, ROWS * EMBED / 4);
  transpose_cast_kernel<<<dim3(QKVC / 32, EMBED / 32), 256, 0, stream>>>(Wqkv, wqkvT, EMBED, QKVC);
  transpose_cast_kernel<<<dim3(EMBED / 32, EMBED / 32), 256, 0, stream>>>(Wout, woutT, EMBED, EMBED);

  gemm_kernel<0><<<dim3(QKVC / 128, ROWS / 128), 256, 0, stream>>>(
      xb, wqkvT, bqkv, qkb, vtb, nullptr, ROWS, QKVC, EMBED);

  attn_kernel<<<dim3(32, 16), 256, 0, stream>>>(qkb, vtb, attnb);

  gemm_kernel<1><<<dim3(EMBED / 128, ROWS / 128), 256, 0, stream>>>(
      attnb, woutT, bout, nullptr, nullptr, out, ROWS, EMBED, EMBED);
}

// Round 5
// 399.016 us; speedup vs baseline: 1.8249x; 1.0548x over previous
//
#include <hip/hip_runtime.h>
#include <hip/hip_bf16.h>

#define EMBED  2048
#define SEQ    2048
#define BATCH  2
#define NHEADS 16
#define HDIM   128
#define QKVC   (3*EMBED)    // 6144
#define ROWS   (BATCH*SEQ)  // 4096

typedef __attribute__((ext_vector_type(8))) short bf16x8;
typedef __attribute__((ext_vector_type(4))) float f32x4;
typedef __attribute__((ext_vector_type(16))) float f32x16;

typedef const __attribute__((address_space(1))) void* gptr1_t;
typedef __attribute__((address_space(3))) void* lptr3_t;

__device__ __forceinline__ void gld16(const unsigned short* g, unsigned short* l) {
  __builtin_amdgcn_global_load_lds((gptr1_t)g, (lptr3_t)l, 16, 0, 0);
}

__device__ __forceinline__ unsigned short f2bf(float f) {
  unsigned int x = __float_as_uint(f);
  unsigned int r = (x + 0x7fffu + ((x >> 16) & 1u)) >> 16;
  return (unsigned short)r;
}

// ---------------- cast x -> bf16 ----------------
__global__ void cast_kernel(const float* __restrict__ in, unsigned short* __restrict__ out, int n4) {
  int i = blockIdx.x * 256 + threadIdx.x;
  if (i >= n4) return;
  float4 v = reinterpret_cast<const float4*>(in)[i];
  ushort4 o;
  o.x = f2bf(v.x); o.y = f2bf(v.y); o.z = f2bf(v.z); o.w = f2bf(v.w);
  reinterpret_cast<ushort4*>(out)[i] = o;
}

// ---------------- transpose + cast W [R][C] f32 -> [C][R] bf16 ----------------
__global__ void transpose_cast_kernel(const float* __restrict__ in, unsigned short* __restrict__ out,
                                      int R, int C) {
  __shared__ float tile[32][33];
  int tx = threadIdx.x & 31, ty = threadIdx.x >> 5;   // 32 x 8
  int c0 = blockIdx.x * 32, r0 = blockIdx.y * 32;
  #pragma unroll
  for (int i = 0; i < 32; i += 8)
    tile[ty + i][tx] = in[(size_t)(r0 + ty + i) * C + c0 + tx];
  __syncthreads();
  #pragma unroll
  for (int i = 0; i < 32; i += 8)
    out[(size_t)(c0 + ty + i) * R + r0 + tx] = f2bf(tile[tx][ty + i]);
}

// ---------------- MFMA GEMM (32x32x16 core): C[M][N] = A[M][K]*BT[N][K]^T + bias ----
// 128x128 tile, BK=32, 4 waves 2x2, wave does 64x64 as 2x2 of 32x32x16 mfma.
// MODE 0: QKV gemm: n0<4096 -> bf16 qk buffer (row stride 4096); else V transposed to vt
// MODE 1: f32 out, row stride N
template<int MODE>
__global__ __launch_bounds__(256)
void gemm_kernel(const unsigned short* __restrict__ A,
                 const unsigned short* __restrict__ BT,
                 const float* __restrict__ bias,
                 unsigned short* __restrict__ outb,
                 unsigned short* __restrict__ vt,
                 float* __restrict__ outf,
                 int M, int N, int K) {
  __shared__ unsigned short As[128 * 32];
  __shared__ unsigned short Bs[128 * 32];
  const int t = threadIdx.x;
  const int lane = t & 63, wave = t >> 6;
  const int l31 = lane & 31, hl = lane >> 5;   // 32x32 operand lane split
  const int wm = wave >> 1, wn = wave & 1;
  const int m0 = blockIdx.y * 128, n0 = blockIdx.x * 128;

  f32x16 acc[2][2] = {};

  // LDS read offsets: row r stores chunk dc at slot sc = dc ^ p(r), p(r)=((r>>2)^r)&3.
  // A-frag (32x32x16): row m = wm*64+i*32+l31, chunk = kstep*2 + hl.
  int aoff[2][2], boff[2][2];
  #pragma unroll
  for (int i = 0; i < 2; ++i) {
    int m = wm * 64 + i * 32 + l31;
    int pm = ((m >> 2) ^ m) & 3;
    int n = wn * 64 + i * 32 + l31;
    int pn = ((n >> 2) ^ n) & 3;
    #pragma unroll
    for (int s = 0; s < 2; ++s) {
      aoff[i][s] = (m * 4 + ((s * 2 + hl) ^ pm)) * 8;
      boff[i][s] = (n * 4 + ((s * 2 + hl) ^ pn)) * 8;
    }
  }
  // staging mapping (2 chunks of 16B per thread per matrix), XOR-swizzled slots
  const int cc0 = t, cc1 = 256 + t;
  const int r0 = cc0 >> 2, s0 = cc0 & 3, d0 = s0 ^ (((r0 >> 2) ^ r0) & 3);
  const int r1 = cc1 >> 2, s1 = cc1 & 3, d1 = s1 ^ (((r1 >> 2) ^ r1) & 3);
  const unsigned short* Ag0 = A  + (size_t)(m0 + r0) * K + d0 * 8;
  const unsigned short* Ag1 = A  + (size_t)(m0 + r1) * K + d1 * 8;
  const unsigned short* Bg0 = BT + (size_t)(n0 + r0) * K + d0 * 8;
  const unsigned short* Bg1 = BT + (size_t)(n0 + r1) * K + d1 * 8;

  for (int k0 = 0; k0 < K; k0 += 32) {
    gld16(Ag0 + k0, &As[cc0 * 8]);
    gld16(Ag1 + k0, &As[cc1 * 8]);
    gld16(Bg0 + k0, &Bs[cc0 * 8]);
    gld16(Bg1 + k0, &Bs[cc1 * 8]);
    __syncthreads();
    #pragma unroll
    for (int s = 0; s < 2; ++s) {
      bf16x8 a0 = *(const bf16x8*)&As[aoff[0][s]];
      bf16x8 a1 = *(const bf16x8*)&As[aoff[1][s]];
      bf16x8 b0 = *(const bf16x8*)&Bs[boff[0][s]];
      bf16x8 b1 = *(const bf16x8*)&Bs[boff[1][s]];
      acc[0][0] = __builtin_amdgcn_mfma_f32_32x32x16_bf16(a0, b0, acc[0][0], 0, 0, 0);
      acc[0][1] = __builtin_amdgcn_mfma_f32_32x32x16_bf16(a0, b1, acc[0][1], 0, 0, 0);
      acc[1][0] = __builtin_amdgcn_mfma_f32_32x32x16_bf16(a1, b0, acc[1][0], 0, 0, 0);
      acc[1][1] = __builtin_amdgcn_mfma_f32_32x32x16_bf16(a1, b1, acc[1][1], 0, 0, 0);
    }
    __syncthreads();
  }

  // epilogue: C/D map: col = l31, row = (reg&3) + 8*(reg>>2) + 4*hl
  #pragma unroll
  for (int i = 0; i < 2; ++i) {
    int rowb = m0 + wm * 64 + i * 32 + 4 * hl;
    #pragma unroll
    for (int j = 0; j < 2; ++j) {
      int col = n0 + wn * 64 + j * 32 + l31;
      float bv = bias[col];
      if (MODE == 1) {
        #pragma unroll
        for (int g = 0; g < 4; ++g)
          #pragma unroll
          for (int rr = 0; rr < 4; ++rr)
            outf[(size_t)(rowb + 8 * g + rr) * N + col] = acc[i][j][4 * g + rr] + bv;
      } else if (n0 < 2 * EMBED) {
        // Q,K region: row stride 4096
        #pragma unroll
        for (int g = 0; g < 4; ++g)
          #pragma unroll
          for (int rr = 0; rr < 4; ++rr)
            outb[(size_t)(rowb + 8 * g + rr) * 4096 + col] = f2bf(acc[i][j][4 * g + rr] + bv);
      } else {
        // V region: write transposed into vt[(b*2048+hd)][s], ushort4 along s
        int hd = col - 2 * EMBED;
        int b = rowb >> 11;
        int sbase = rowb & 2047;
        #pragma unroll
        for (int g = 0; g < 4; ++g) {
          ushort4 w;
          w.x = f2bf(acc[i][j][4 * g + 0] + bv);
          w.y = f2bf(acc[i][j][4 * g + 1] + bv);
          w.z = f2bf(acc[i][j][4 * g + 2] + bv);
          w.w = f2bf(acc[i][j][4 * g + 3] + bv);
          *(ushort4*)&vt[(((size_t)(b << 11) + hd) << 11) + sbase + 8 * g] = w;
        }
      }
    }
  }
}

// ---------------- flash attention (S^T form, double-buffered K/V) ----------------
// grid: (x=32 bh, y=16 q-tile pairs) -> same-bh blocks on same XCD (linear id mod 8)
__global__ __launch_bounds__(256)
void attn_kernel(const unsigned short* __restrict__ qk,   // [4096][4096] Q|K bf16
                 const unsigned short* __restrict__ vt,   // [32*128][2048] V^T bf16
                 unsigned short* __restrict__ outb) {     // [4096][2048] bf16
  __shared__ unsigned short Ks[2][64 * 128];
  __shared__ unsigned short Vs[2][64 * 128];
  __shared__ unsigned short Ps[4][16 * 72];
  const int t = threadIdx.x;
  const int lane = t & 63, wave = t >> 6;
  const int quad = lane >> 4, l16 = lane & 15;
  const int bh = blockIdx.x;
  const int pair = blockIdx.y;
  const int b = bh >> 4, h = bh & 15;
  const size_t rowbase = (size_t)b * SEQ;
  const int hq = h * HDIM;
  const unsigned short* vbase = vt + ((size_t)bh * HDIM) * SEQ;

  const float SC = 0.08838834764831845f * 1.4426950408889634f; // 1/sqrt(128)*log2(e)

  #pragma unroll
  for (int half = 0; half < 2; ++half) {
    const int qt = half ? (31 - pair) : pair;
    const int qw0 = qt * 64 + wave * 16;

    bf16x8 qf[4];
    {
      const unsigned short* qrow = qk + (size_t)(rowbase + qw0 + l16) * 4096 + hq + quad * 8;
      #pragma unroll
      for (int s = 0; s < 4; ++s) qf[s] = *(const bf16x8*)(qrow + s * 32);
    }

    f32x4 o[8] = {};
    float mrow = -1e30f, lrow = 0.f;

    // prologue: stage tile 0 into buffer 0
    #pragma unroll
    for (int i = 0; i < 4; ++i) {
      int cc = i * 256 + t;
      int kv = cc >> 4, sc = cc & 15;
      int dc = sc ^ (kv & 15);
      gld16(qk + (size_t)(rowbase + kv) * 4096 + EMBED + hq + dc * 8, &Ks[0][cc * 8]);
    }
    #pragma unroll
    for (int i = 0; i < 4; ++i) {
      int cc = i * 256 + t;
      int d = cc >> 3, c = cc & 7;
      int dc = c ^ (d & 7);
      gld16(vbase + (size_t)d * SEQ + dc * 8, &Vs[0][cc * 8]);
    }

    for (int j = 0; j <= qt; ++j) {
      const int cur = j & 1;
      __syncthreads();   // buf[cur] ready; all reads of buf[cur^1] complete

      if (j < qt) {      // prefetch tile j+1, overlapped with compute below
        const int kv1 = (j + 1) * 64;
        #pragma unroll
        for (int i = 0; i < 4; ++i) {
          int cc = i * 256 + t;
          int kv = cc >> 4, sc = cc & 15;
          int dc = sc ^ (kv & 15);
          gld16(qk + (size_t)(rowbase + kv1 + kv) * 4096 + EMBED + hq + dc * 8, &Ks[cur ^ 1][cc * 8]);
        }
        #pragma unroll
        for (int i = 0; i < 4; ++i) {
          int cc = i * 256 + t;
          int d = cc >> 3, c = cc & 7;
          int dc = c ^ (d & 7);
          gld16(vbase + (size_t)d * SEQ + kv1 + dc * 8, &Vs[cur ^ 1][cc * 8]);
        }
      }

      const int kv0 = j * 64;
      f32x4 sacc[4] = {};
      #pragma unroll
      for (int nb = 0; nb < 4; ++nb) {
        int kvr = nb * 16 + l16;
        #pragma unroll
        for (int ks = 0; ks < 4; ++ks) {
          int dc2 = (ks * 4 + quad) ^ (kvr & 15);
          bf16x8 kb = *(const bf16x8*)&Ks[cur][(kvr * 16 + dc2) * 8];
          sacc[nb] = __builtin_amdgcn_mfma_f32_16x16x32_bf16(kb, qf[ks], sacc[nb], 0, 0, 0);
        }
      }

      float p[4][4];
      float smax = -1e30f;
      if (j == qt) {
        const int qg = qw0 + l16;
        #pragma unroll
        for (int nb = 0; nb < 4; ++nb)
          #pragma unroll
          for (int r = 0; r < 4; ++r) {
            float v = sacc[nb][r] * SC;
            if ((kv0 + nb * 16 + quad * 4 + r) > qg) v = -1e30f;
            p[nb][r] = v;
            smax = fmaxf(smax, v);
          }
      } else {
        #pragma unroll
        for (int nb = 0; nb < 4; ++nb)
          #pragma unroll
          for (int r = 0; r < 4; ++r) {
            float v = sacc[nb][r] * SC;
            p[nb][r] = v;
            smax = fmaxf(smax, v);
          }
      }
      smax = fmaxf(smax, __shfl_xor(smax, 16));
      smax = fmaxf(smax, __shfl_xor(smax, 32));

      const float mold = mrow;
      const unsigned long long grew = __ballot(smax > mold);
      const float mnew = fmaxf(mold, smax);
      mrow = mnew;

      float rs = 0.f;
      #pragma unroll
      for (int nb = 0; nb < 4; ++nb)
        #pragma unroll
        for (int r = 0; r < 4; ++r) {
          float pv = exp2f(p[nb][r] - mnew);
          p[nb][r] = pv;
          rs += pv;
        }
      rs += __shfl_xor(rs, 16);
      rs += __shfl_xor(rs, 32);

      unsigned short* pw = &Ps[wave][0];
      #pragma unroll
      for (int nb = 0; nb < 4; ++nb) {
        __hip_bfloat162 lo = __float22bfloat162_rn(make_float2(p[nb][0], p[nb][1]));
        __hip_bfloat162 hi = __float22bfloat162_rn(make_float2(p[nb][2], p[nb][3]));
        ushort4 w;
        w.x = *(unsigned short*)&lo.x; w.y = *(unsigned short*)&lo.y;
        w.z = *(unsigned short*)&hi.x; w.w = *(unsigned short*)&hi.y;
        *(ushort4*)&pw[l16 * 72 + nb * 16 + quad * 4] = w;
      }

      if (grew) {   // wave-uniform: some q-row's max increased -> rescale O and lrow
        float alpha = exp2f(mold - mnew);   // ==1 for rows that didn't grow
        lrow = lrow * alpha + rs;
        #pragma unroll
        for (int r = 0; r < 4; ++r) {
          float av = __shfl(alpha, quad * 4 + r, 16);
          #pragma unroll
          for (int db = 0; db < 8; ++db) o[db][r] *= av;
        }
      } else {
        lrow += rs;
      }

      asm volatile("s_waitcnt lgkmcnt(0)" ::: "memory");
      bf16x8 pa[2];
      #pragma unroll
      for (int ks2 = 0; ks2 < 2; ++ks2)
        pa[ks2] = *(const bf16x8*)&pw[l16 * 72 + ks2 * 32 + quad * 8];

      #pragma unroll
      for (int db = 0; db < 8; ++db) {
        int d = db * 16 + l16;
        #pragma unroll
        for (int ks2 = 0; ks2 < 2; ++ks2) {
          int dc = (ks2 * 4 + quad) ^ (d & 7);
          bf16x8 vb = *(const bf16x8*)&Vs[cur][(d * 8 + dc) * 8];
          o[db] = __builtin_amdgcn_mfma_f32_16x16x32_bf16(pa[ks2], vb, o[db], 0, 0, 0);
        }
      }
    }

    #pragma unroll
    for (int r = 0; r < 4; ++r) {
      float lr = __shfl(lrow, quad * 4 + r, 16);
      float inv = 1.0f / lr;
      size_t row = rowbase + qw0 + quad * 4 + r;
      #pragma unroll
      for (int db = 0; db < 8; ++db)
        outb[row * EMBED + hq + db * 16 + l16] = f2bf(o[db][r] * inv);
    }
    __syncthreads();  // all waves done with buffers before next half restages
  }
}

extern "C" void kernel_launch(void* const* d_in, const int* in_sizes, int n_in,
                              void* d_out, int out_size, void* d_ws, size_t ws_size,
                              hipStream_t stream) {
  const float* x    = (const float*)d_in[0];
  const float* Wqkv = (const float*)d_in[1];
  const float* bqkv = (const float*)d_in[2];
  const float* Wout = (const float*)d_in[3];
  const float* bout = (const float*)d_in[4];
  float* out = (float*)d_out;

  unsigned short* xb    = (unsigned short*)d_ws;
  unsigned short* wqkvT = xb    + (size_t)ROWS * EMBED;    // [6144][2048]
  unsigned short* woutT = wqkvT + (size_t)EMBED * QKVC;    // [2048][2048]
  unsigned short* qkb   = woutT + (size_t)EMBED * EMBED;   // [4096][4096] Q|K
  unsigned short* vtb   = qkb   + (size_t)ROWS * 4096;     // [32*128][2048] V^T
  unsigned short* attnb = vtb   + (size_t)32 * HDIM * SEQ; // [4096][2048]

  cast_kernel<<<dim3((ROWS * EMBED / 4 + 255) / 256), 256, 0, stream>>>(x, xb, ROWS * EMBED / 4);
  transpose_cast_kernel<<<dim3(QKVC / 32, EMBED / 32), 256, 0, stream>>>(Wqkv, wqkvT, EMBED, QKVC);
  transpose_cast_kernel<<<dim3(EMBED / 32, EMBED / 32), 256, 0, stream>>>(Wout, woutT, EMBED, EMBED);

  gemm_kernel<0><<<dim3(QKVC / 128, ROWS / 128), 256, 0, stream>>>(
      xb, wqkvT, bqkv, qkb, vtb, nullptr, ROWS, QKVC, EMBED);

  attn_kernel<<<dim3(32, 16), 256, 0, stream>>>(qkb, vtb, attnb);

  gemm_kernel<1><<<dim3(EMBED / 128, ROWS / 128), 256, 0, stream>>>(
      attnb, woutT, bout, nullptr, nullptr, out, ROWS, EMBED, EMBED);
}

// Round 6
// 391.418 us; speedup vs baseline: 1.8603x; 1.0194x over previous
//
#include <hip/hip_runtime.h>
#include <hip/hip_bf16.h>

#define EMBED  2048
#define SEQ    2048
#define BATCH  2
#define NHEADS 16
#define HDIM   128
#define QKVC   (3*EMBED)    // 6144
#define ROWS   (BATCH*SEQ)  // 4096

typedef __attribute__((ext_vector_type(8))) short bf16x8;
typedef __attribute__((ext_vector_type(4))) float f32x4;
typedef __attribute__((ext_vector_type(16))) float f32x16;

typedef const __attribute__((address_space(1))) void* gptr1_t;
typedef __attribute__((address_space(3))) void* lptr3_t;

__device__ __forceinline__ void gld16(const unsigned short* g, unsigned short* l) {
  __builtin_amdgcn_global_load_lds((gptr1_t)g, (lptr3_t)l, 16, 0, 0);
}

__device__ __forceinline__ unsigned short f2bf(float f) {
  unsigned int x = __float_as_uint(f);
  unsigned int r = (x + 0x7fffu + ((x >> 16) & 1u)) >> 16;
  return (unsigned short)r;
}

// ---------------- cast x -> bf16 ----------------
__global__ void cast_kernel(const float* __restrict__ in, unsigned short* __restrict__ out, int n4) {
  int i = blockIdx.x * 256 + threadIdx.x;
  if (i >= n4) return;
  float4 v = reinterpret_cast<const float4*>(in)[i];
  ushort4 o;
  o.x = f2bf(v.x); o.y = f2bf(v.y); o.z = f2bf(v.z); o.w = f2bf(v.w);
  reinterpret_cast<ushort4*>(out)[i] = o;
}

// ---------------- transpose + cast W [R][C] f32 -> [C][R] bf16 ----------------
__global__ void transpose_cast_kernel(const float* __restrict__ in, unsigned short* __restrict__ out,
                                      int R, int C) {
  __shared__ float tile[32][33];
  int tx = threadIdx.x & 31, ty = threadIdx.x >> 5;   // 32 x 8
  int c0 = blockIdx.x * 32, r0 = blockIdx.y * 32;
  #pragma unroll
  for (int i = 0; i < 32; i += 8)
    tile[ty + i][tx] = in[(size_t)(r0 + ty + i) * C + c0 + tx];
  __syncthreads();
  #pragma unroll
  for (int i = 0; i < 32; i += 8)
    out[(size_t)(c0 + ty + i) * R + r0 + tx] = f2bf(tile[tx][ty + i]);
}

// ---------------- MFMA GEMM (32x32x16 core, BK=64): C = A * BT^T + bias ----------
// 128x128 tile, BK=64 staged as two proven 128x32 XOR-swizzled sub-tiles.
// 4 waves 2x2, wave does 64x64 as 2x2 of 32x32x16 mfma; 16 MFMA per K-iter.
// MODE 0: QKV gemm: n0<4096 -> bf16 qk buffer (row stride 4096); else V transposed to vt
// MODE 1: f32 out, row stride N
template<int MODE>
__global__ __launch_bounds__(256)
void gemm_kernel(const unsigned short* __restrict__ A,
                 const unsigned short* __restrict__ BT,
                 const float* __restrict__ bias,
                 unsigned short* __restrict__ outb,
                 unsigned short* __restrict__ vt,
                 float* __restrict__ outf,
                 int M, int N, int K) {
  __shared__ unsigned short As[2 * 128 * 32];   // two BK=32 sub-tiles
  __shared__ unsigned short Bs[2 * 128 * 32];
  const int t = threadIdx.x;
  const int lane = t & 63, wave = t >> 6;
  const int l31 = lane & 31, hl = lane >> 5;
  const int wm = wave >> 1, wn = wave & 1;
  const int m0 = blockIdx.y * 128, n0 = blockIdx.x * 128;

  f32x16 acc[2][2] = {};

  // MFMA LDS read offsets: sub-tile st = s4>>1, chunk c = (s4&1)*2 + hl,
  // slot = c ^ p(row), p(r) = ((r>>2)^r)&3.
  int aoff[2][4], boff[2][4];
  #pragma unroll
  for (int i = 0; i < 2; ++i) {
    int m = wm * 64 + i * 32 + l31;
    int pm = ((m >> 2) ^ m) & 3;
    int n = wn * 64 + i * 32 + l31;
    int pn = ((n >> 2) ^ n) & 3;
    #pragma unroll
    for (int s4 = 0; s4 < 4; ++s4) {
      int st = s4 >> 1, c = (s4 & 1) * 2 + hl;
      aoff[i][s4] = st * 4096 + (m * 4 + (c ^ pm)) * 8;
      boff[i][s4] = st * 4096 + (n * 4 + (c ^ pn)) * 8;
    }
  }
  // staging: 1024 chunks of 16B per matrix; thread t does cc = i*256 + t
  int ldso[4];
  const unsigned short* Ag[4];
  const unsigned short* Bg[4];
  #pragma unroll
  for (int i = 0; i < 4; ++i) {
    int cc = i * 256 + t;
    int st = cc >> 9, w = cc & 511;
    int r = w >> 2, s = w & 3;
    int d = s ^ (((r >> 2) ^ r) & 3);
    ldso[i] = st * 4096 + w * 8;
    Ag[i] = A  + (size_t)(m0 + r) * K + st * 32 + d * 8;
    Bg[i] = BT + (size_t)(n0 + r) * K + st * 32 + d * 8;
  }

  for (int k0 = 0; k0 < K; k0 += 64) {
    #pragma unroll
    for (int i = 0; i < 4; ++i) gld16(Ag[i] + k0, &As[ldso[i]]);
    #pragma unroll
    for (int i = 0; i < 4; ++i) gld16(Bg[i] + k0, &Bs[ldso[i]]);
    __syncthreads();
    #pragma unroll
    for (int s4 = 0; s4 < 4; ++s4) {
      bf16x8 a0 = *(const bf16x8*)&As[aoff[0][s4]];
      bf16x8 a1 = *(const bf16x8*)&As[aoff[1][s4]];
      bf16x8 b0 = *(const bf16x8*)&Bs[boff[0][s4]];
      bf16x8 b1 = *(const bf16x8*)&Bs[boff[1][s4]];
      acc[0][0] = __builtin_amdgcn_mfma_f32_32x32x16_bf16(a0, b0, acc[0][0], 0, 0, 0);
      acc[0][1] = __builtin_amdgcn_mfma_f32_32x32x16_bf16(a0, b1, acc[0][1], 0, 0, 0);
      acc[1][0] = __builtin_amdgcn_mfma_f32_32x32x16_bf16(a1, b0, acc[1][0], 0, 0, 0);
      acc[1][1] = __builtin_amdgcn_mfma_f32_32x32x16_bf16(a1, b1, acc[1][1], 0, 0, 0);
    }
    __syncthreads();
  }

  // epilogue: C/D map: col = l31, row = (reg&3) + 8*(reg>>2) + 4*hl
  #pragma unroll
  for (int i = 0; i < 2; ++i) {
    int rowb = m0 + wm * 64 + i * 32 + 4 * hl;
    #pragma unroll
    for (int j = 0; j < 2; ++j) {
      int col = n0 + wn * 64 + j * 32 + l31;
      float bv = bias[col];
      if (MODE == 1) {
        #pragma unroll
        for (int g = 0; g < 4; ++g)
          #pragma unroll
          for (int rr = 0; rr < 4; ++rr)
            outf[(size_t)(rowb + 8 * g + rr) * N + col] = acc[i][j][4 * g + rr] + bv;
      } else if (n0 < 2 * EMBED) {
        // Q,K region: row stride 4096
        #pragma unroll
        for (int g = 0; g < 4; ++g)
          #pragma unroll
          for (int rr = 0; rr < 4; ++rr)
            outb[(size_t)(rowb + 8 * g + rr) * 4096 + col] = f2bf(acc[i][j][4 * g + rr] + bv);
      } else {
        // V region: write transposed into vt[(b*2048+hd)][s], ushort4 along s
        int hd = col - 2 * EMBED;
        int b = rowb >> 11;
        int sbase = rowb & 2047;
        #pragma unroll
        for (int g = 0; g < 4; ++g) {
          ushort4 w;
          w.x = f2bf(acc[i][j][4 * g + 0] + bv);
          w.y = f2bf(acc[i][j][4 * g + 1] + bv);
          w.z = f2bf(acc[i][j][4 * g + 2] + bv);
          w.w = f2bf(acc[i][j][4 * g + 3] + bv);
          *(ushort4*)&vt[(((size_t)(b << 11) + hd) << 11) + sbase + 8 * g] = w;
        }
      }
    }
  }
}

// ---------------- flash attention (S^T form, double-buffered K/V) ----------------
// grid: (x=32 bh, y=16 q-tile pairs) -> same-bh blocks on same XCD (linear id mod 8)
__global__ __launch_bounds__(256)
void attn_kernel(const unsigned short* __restrict__ qk,   // [4096][4096] Q|K bf16
                 const unsigned short* __restrict__ vt,   // [32*128][2048] V^T bf16
                 unsigned short* __restrict__ outb) {     // [4096][2048] bf16
  __shared__ unsigned short Ks[2][64 * 128];
  __shared__ unsigned short Vs[2][64 * 128];
  __shared__ unsigned short Ps[4][16 * 72];
  const int t = threadIdx.x;
  const int lane = t & 63, wave = t >> 6;
  const int quad = lane >> 4, l16 = lane & 15;
  const int bh = blockIdx.x;
  const int pair = blockIdx.y;
  const int b = bh >> 4, h = bh & 15;
  const size_t rowbase = (size_t)b * SEQ;
  const int hq = h * HDIM;
  const unsigned short* vbase = vt + ((size_t)bh * HDIM) * SEQ;

  const float SC = 0.08838834764831845f * 1.4426950408889634f; // 1/sqrt(128)*log2(e)

  #pragma unroll
  for (int half = 0; half < 2; ++half) {
    const int qt = half ? (31 - pair) : pair;
    const int qw0 = qt * 64 + wave * 16;

    bf16x8 qf[4];
    {
      const unsigned short* qrow = qk + (size_t)(rowbase + qw0 + l16) * 4096 + hq + quad * 8;
      #pragma unroll
      for (int s = 0; s < 4; ++s) qf[s] = *(const bf16x8*)(qrow + s * 32);
    }

    f32x4 o[8] = {};
    float mrow = -1e30f, lrow = 0.f;

    // prologue: stage tile 0 into buffer 0
    #pragma unroll
    for (int i = 0; i < 4; ++i) {
      int cc = i * 256 + t;
      int kv = cc >> 4, sc = cc & 15;
      int dc = sc ^ (kv & 15);
      gld16(qk + (size_t)(rowbase + kv) * 4096 + EMBED + hq + dc * 8, &Ks[0][cc * 8]);
    }
    #pragma unroll
    for (int i = 0; i < 4; ++i) {
      int cc = i * 256 + t;
      int d = cc >> 3, c = cc & 7;
      int dc = c ^ (d & 7);
      gld16(vbase + (size_t)d * SEQ + dc * 8, &Vs[0][cc * 8]);
    }

    for (int j = 0; j <= qt; ++j) {
      const int cur = j & 1;
      __syncthreads();   // buf[cur] ready; all reads of buf[cur^1] complete

      if (j < qt) {      // prefetch tile j+1, overlapped with compute below
        const int kv1 = (j + 1) * 64;
        #pragma unroll
        for (int i = 0; i < 4; ++i) {
          int cc = i * 256 + t;
          int kv = cc >> 4, sc = cc & 15;
          int dc = sc ^ (kv & 15);
          gld16(qk + (size_t)(rowbase + kv1 + kv) * 4096 + EMBED + hq + dc * 8, &Ks[cur ^ 1][cc * 8]);
        }
        #pragma unroll
        for (int i = 0; i < 4; ++i) {
          int cc = i * 256 + t;
          int d = cc >> 3, c = cc & 7;
          int dc = c ^ (d & 7);
          gld16(vbase + (size_t)d * SEQ + kv1 + dc * 8, &Vs[cur ^ 1][cc * 8]);
        }
      }

      const int kv0 = j * 64;
      f32x4 sacc[4] = {};
      #pragma unroll
      for (int nb = 0; nb < 4; ++nb) {
        int kvr = nb * 16 + l16;
        #pragma unroll
        for (int ks = 0; ks < 4; ++ks) {
          int dc2 = (ks * 4 + quad) ^ (kvr & 15);
          bf16x8 kb = *(const bf16x8*)&Ks[cur][(kvr * 16 + dc2) * 8];
          sacc[nb] = __builtin_amdgcn_mfma_f32_16x16x32_bf16(kb, qf[ks], sacc[nb], 0, 0, 0);
        }
      }

      float p[4][4];
      float smax = -1e30f;
      if (j == qt) {
        const int qg = qw0 + l16;
        #pragma unroll
        for (int nb = 0; nb < 4; ++nb)
          #pragma unroll
          for (int r = 0; r < 4; ++r) {
            float v = sacc[nb][r] * SC;
            if ((kv0 + nb * 16 + quad * 4 + r) > qg) v = -1e30f;
            p[nb][r] = v;
            smax = fmaxf(smax, v);
          }
      } else {
        #pragma unroll
        for (int nb = 0; nb < 4; ++nb)
          #pragma unroll
          for (int r = 0; r < 4; ++r) {
            float v = sacc[nb][r] * SC;
            p[nb][r] = v;
            smax = fmaxf(smax, v);
          }
      }
      smax = fmaxf(smax, __shfl_xor(smax, 16));
      smax = fmaxf(smax, __shfl_xor(smax, 32));

      const float mold = mrow;
      const unsigned long long grew = __ballot(smax > mold);
      const float mnew = fmaxf(mold, smax);
      mrow = mnew;

      float rs = 0.f;
      #pragma unroll
      for (int nb = 0; nb < 4; ++nb)
        #pragma unroll
        for (int r = 0; r < 4; ++r) {
          float pv = exp2f(p[nb][r] - mnew);
          p[nb][r] = pv;
          rs += pv;
        }
      rs += __shfl_xor(rs, 16);
      rs += __shfl_xor(rs, 32);

      unsigned short* pw = &Ps[wave][0];
      #pragma unroll
      for (int nb = 0; nb < 4; ++nb) {
        __hip_bfloat162 lo = __float22bfloat162_rn(make_float2(p[nb][0], p[nb][1]));
        __hip_bfloat162 hi = __float22bfloat162_rn(make_float2(p[nb][2], p[nb][3]));
        ushort4 w;
        w.x = *(unsigned short*)&lo.x; w.y = *(unsigned short*)&lo.y;
        w.z = *(unsigned short*)&hi.x; w.w = *(unsigned short*)&hi.y;
        *(ushort4*)&pw[l16 * 72 + nb * 16 + quad * 4] = w;
      }

      if (grew) {   // wave-uniform: some q-row's max increased -> rescale O and lrow
        float alpha = exp2f(mold - mnew);   // ==1 for rows that didn't grow
        lrow = lrow * alpha + rs;
        #pragma unroll
        for (int r = 0; r < 4; ++r) {
          float av = __shfl(alpha, quad * 4 + r, 16);
          #pragma unroll
          for (int db = 0; db < 8; ++db) o[db][r] *= av;
        }
      } else {
        lrow += rs;
      }

      asm volatile("s_waitcnt lgkmcnt(0)" ::: "memory");
      bf16x8 pa[2];
      #pragma unroll
      for (int ks2 = 0; ks2 < 2; ++ks2)
        pa[ks2] = *(const bf16x8*)&pw[l16 * 72 + ks2 * 32 + quad * 8];

      #pragma unroll
      for (int db = 0; db < 8; ++db) {
        int d = db * 16 + l16;
        #pragma unroll
        for (int ks2 = 0; ks2 < 2; ++ks2) {
          int dc = (ks2 * 4 + quad) ^ (d & 7);
          bf16x8 vb = *(const bf16x8*)&Vs[cur][(d * 8 + dc) * 8];
          o[db] = __builtin_amdgcn_mfma_f32_16x16x32_bf16(pa[ks2], vb, o[db], 0, 0, 0);
        }
      }
    }

    #pragma unroll
    for (int r = 0; r < 4; ++r) {
      float lr = __shfl(lrow, quad * 4 + r, 16);
      float inv = 1.0f / lr;
      size_t row = rowbase + qw0 + quad * 4 + r;
      #pragma unroll
      for (int db = 0; db < 8; ++db)
        outb[row * EMBED + hq + db * 16 + l16] = f2bf(o[db][r] * inv);
    }
    __syncthreads();  // all waves done with buffers before next half restages
  }
}

extern "C" void kernel_launch(void* const* d_in, const int* in_sizes, int n_in,
                              void* d_out, int out_size, void* d_ws, size_t ws_size,
                              hipStream_t stream) {
  const float* x    = (const float*)d_in[0];
  const float* Wqkv = (const float*)d_in[1];
  const float* bqkv = (const float*)d_in[2];
  const float* Wout = (const float*)d_in[3];
  const float* bout = (const float*)d_in[4];
  float* out = (float*)d_out;

  unsigned short* xb    = (unsigned short*)d_ws;
  unsigned short* wqkvT = xb    + (size_t)ROWS * EMBED;    // [6144][2048]
  unsigned short* woutT = wqkvT + (size_t)EMBED * QKVC;    // [2048][2048]
  unsigned short* qkb   = woutT + (size_t)EMBED * EMBED;   // [4096][4096] Q|K
  unsigned short* vtb   = qkb   + (size_t)ROWS * 4096;     // [32*128][2048] V^T
  unsigned short* attnb = vtb   + (size_t)32 * HDIM * SEQ; // [4096][2048]

  cast_kernel<<<dim3((ROWS * EMBED / 4 + 255) / 256), 256, 0, stream>>>(x, xb, ROWS * EMBED / 4);
  transpose_cast_kernel<<<dim3(QKVC / 32, EMBED / 32), 256, 0, stream>>>(Wqkv, wqkvT, EMBED, QKVC);
  transpose_cast_kernel<<<dim3(EMBED / 32, EMBED / 32), 256, 0, stream>>>(Wout, woutT, EMBED, EMBED);

  gemm_kernel<0><<<dim3(QKVC / 128, ROWS / 128), 256, 0, stream>>>(
      xb, wqkvT, bqkv, qkb, vtb, nullptr, ROWS, QKVC, EMBED);

  attn_kernel<<<dim3(32, 16), 256, 0, stream>>>(qkb, vtb, attnb);

  gemm_kernel<1><<<dim3(EMBED / 128, ROWS / 128), 256, 0, stream>>>(
      attnb, woutT, bout, nullptr, nullptr, out, ROWS, EMBED, EMBED);
}